// Round 13
// baseline (786.116 us; speedup 1.0000x reference)
//
#include <hip/hip_runtime.h>
#include <hip/hip_bf16.h>

typedef __attribute__((ext_vector_type(8))) short short8;
typedef __attribute__((ext_vector_type(4))) float floatx4;

#define IN_DIM  4096
#define OUT_DIM 4096
#define MROWS   16384
#define GSIZE   128

template <int N> struct IC { static constexpr int value = N; };

__device__ __forceinline__ unsigned short f2bf(float f) {
    unsigned int u = __builtin_bit_cast(unsigned int, f);
    u = (u + 0x7fffu + ((u >> 16) & 1u)) >> 16;
    return (unsigned short)u;
}

#define GLD16(gsrc, ldst)                                                     \
    __builtin_amdgcn_global_load_lds(                                         \
        (const __attribute__((address_space(1))) unsigned int*)(const void*)(gsrc), \
        (__attribute__((address_space(3))) unsigned int*)(void*)(ldst),       \
        16, 0, 0)

// ---------------------------------------------------------------- convert x
__global__ void convert_x(const float* __restrict__ x,
                          unsigned short* __restrict__ xb, int n8) {
    int stride = gridDim.x * blockDim.x;
    for (int i = blockIdx.x * blockDim.x + threadIdx.x; i < n8; i += stride) {
        const float4* xf = (const float4*)x;
        float4 f0 = xf[2 * i];
        float4 f1 = xf[2 * i + 1];
        union { unsigned short u[8]; uint4 v; } pk;
        pk.u[0] = f2bf(f0.x); pk.u[1] = f2bf(f0.y);
        pk.u[2] = f2bf(f0.z); pk.u[3] = f2bf(f0.w);
        pk.u[4] = f2bf(f1.x); pk.u[5] = f2bf(f1.y);
        pk.u[6] = f2bf(f1.z); pk.u[7] = f2bf(f1.w);
        ((uint4*)xb)[i] = pk.v;
    }
}

// ---------------------------------------------------------------- decode W
__global__ void decode_w(const int* __restrict__ pw,
                         const float* __restrict__ norms,
                         const float* __restrict__ s1,
                         const float* __restrict__ s2,
                         const float* __restrict__ cent,
                         unsigned short* __restrict__ W) {
    int row  = blockIdx.x * 4 + (threadIdx.x >> 6);
    int lane = threadIdx.x & 63;
    float nrm = norms[row];
    int c0 = pw[(size_t)row * GSIZE + lane];
    int c1 = pw[(size_t)row * GSIZE + lane + 64];
    float e0 = cent[c0] * nrm * s2[lane];
    float e1 = cent[c1] * nrm * s2[lane + 64];
#pragma unroll
    for (int it = 0; it < 7; ++it) {
        float a = e0, b = e1;
        e0 = a + b;
        e1 = a - b;
    }
    const float inv = 0.08838834764831845f; // 1/sqrt(128)
    int o = row >> 5, g = row & 31;
    unsigned short* wr = W + (size_t)o * IN_DIM + g * GSIZE;
    wr[lane]      = f2bf(e0 * inv * s1[lane]);
    wr[lane + 64] = f2bf(e1 * inv * s1[lane + 64]);
}

// ---------------------------------------------------------------- GEMM
// 256x256 tile, BK=64, 8 waves (2M x 4N), 16x16x32 MFMA (proven 0-conflict
// read shape). READ-AHEAD 4-phase schedule: reads grouped 8/4/8/4 per
// phase, each group exactly ONE phase before its consuming MFMA cluster,
// so all operand lgkm waits are compiler-counted and COLD (R6's per-phase
// hot lgkmcnt(0) drain was the serializer). No explicit lgkm at all.
//
// Clusters (16 MFMA each): c0=(m0-3,ks0) c1=(m4-7,ks0) c2=(m0-3,ks1)
// c3=(m4-7,ks1), each over all 4 n-frags.
// Frag groups: aL[4] (A m0-3), aH[4] (A m4-7), b0k[4] (B ks0), b1k[4] (B ks1).
//
// Per tile j (BF=j&1, OF=BF^1):
//  p0: read g1 = aH<-A m4-7 ks0 (4); stage A1,B1(j+1)->OF; MFMA c0; bar
//  p1: read g2 = aL<-A m0-3 ks1 + b1k (8);               MFMA c1; bar
//  p2: read g3 = aH<-A m4-7 ks1 (4);                     MFMA c2; bar
//  p3: stage A0,B0(j+2)->BF; vmcnt(4); bar;
//      read g0(j+1) = aL + b0k from OF (8);              MFMA c3; bar
//
// Hazard ledger (on read-COMPLETION, enforced by compiler operand-waits +
// end-barriers): A1/B1-of-OF reads complete <= p3(j-1) -> stage@p0(j) ok.
// A0/B0-of-BF reads complete <= c2@p2(j) -> stage@p3(j) ok. vmcnt(4)@p3
// leaves only own 4 loads -> tile j+1 fully landed (oldest waited load
// issued p0(j), 3 phases ~3900cy cold); bar globalizes before g0(j+1).
__global__ __launch_bounds__(512, 2)
void gemm_bf16(const unsigned short* __restrict__ Xg,
               const unsigned short* __restrict__ Wg,
               const float* __restrict__ bias,
               float* __restrict__ out) {
    __shared__ unsigned short As[2][256][64];
    __shared__ unsigned short Bs[2][256][64];

    // bijective XCD swizzle (1024 blocks % 8 == 0); consecutive ids share mt
    int id = (blockIdx.x & 7) * 128 + (blockIdx.x >> 3);
    int mt = id >> 4, nt = id & 15;
    int m0 = mt * 256, n0 = nt * 256;

    int tid  = threadIdx.x;
    int lane = tid & 63;
    int wid  = tid >> 6;
    int wm = wid >> 2, wn = wid & 3;   // wave tile: rows wm*128+, cols wn*64+

    // staging: thread handles 16B phys chunk cp0 of rows sr0 / sr0+64(+128)
    int sr0 = tid >> 3;        // 0..63
    int cp0 = tid & 7;         // physical chunk position
    int sg0 = cp0 ^ (sr0 & 7); // global chunk (inverse swizzle)

// A halves interleaved: h=0 -> rows [0,64)u[128,192) (m-frags 0-3),
//                       h=1 -> rows [64,128)u[192,256) (m-frags 4-7)
#define STG_AH(bufc, h, j) do {                                               \
    const unsigned short* _s =                                                \
        Xg + (size_t)(m0 + (h)*64 + sr0) * IN_DIM + (size_t)(j)*64 + sg0*8;   \
    GLD16(_s,                 &As[bufc][(h)*64 + sr0][cp0 * 8]);              \
    GLD16(_s + 128 * IN_DIM,  &As[bufc][128 + (h)*64 + sr0][cp0 * 8]);        \
  } while (0)
// B halves contiguous: h=0 -> rows [0,128), h=1 -> rows [128,256)
#define STG_BH(bufc, h, j) do {                                               \
    const unsigned short* _s =                                                \
        Wg + (size_t)(n0 + (h)*128 + sr0) * IN_DIM + (size_t)(j)*64 + sg0*8;  \
    GLD16(_s,                &Bs[bufc][(h)*128 + sr0][cp0 * 8]);              \
    GLD16(_s + 64 * IN_DIM,  &Bs[bufc][(h)*128 + sr0 + 64][cp0 * 8]);         \
  } while (0)

    int rl = lane & 15, kc = lane >> 4;
    short8 aL[4], aH[4], b0k[4], b1k[4];
    floatx4 acc[8][4] = {};

#define RD_A(BFc, m, ks)                                                      \
    (*(const short8*)&As[BFc][wm*128 + (m)*16 + rl]                           \
         [((((ks)*4 + kc) ^ (rl & 7)) << 3)])
#define RD_B(BFc, n, ks)                                                      \
    (*(const short8*)&Bs[BFc][wn*64 + (n)*16 + rl]                            \
         [((((ks)*4 + kc) ^ (rl & 7)) << 3)])

#define LD_AL(BFc, ks) do { _Pragma("unroll")                                 \
    for (int m = 0; m < 4; ++m) aL[m] = RD_A(BFc, m, ks); } while (0)
#define LD_AH(BFc, ks) do { _Pragma("unroll")                                 \
    for (int m = 0; m < 4; ++m) aH[m] = RD_A(BFc, m + 4, ks); } while (0)
#define LD_BK(BFc, dst, ks) do { _Pragma("unroll")                            \
    for (int n = 0; n < 4; ++n) dst[n] = RD_B(BFc, n, ks); } while (0)

#define MFMA_C(AF, BG, MO) do {                                               \
    __builtin_amdgcn_s_setprio(1);                                            \
    _Pragma("unroll") for (int m = 0; m < 4; ++m) {                           \
      _Pragma("unroll") for (int n = 0; n < 4; ++n)                           \
        acc[m + (MO)][n] = __builtin_amdgcn_mfma_f32_16x16x32_bf16(           \
            AF[m], BG[n], acc[m + (MO)][n], 0, 0, 0);                         \
    }                                                                         \
    __builtin_amdgcn_s_setprio(0);                                            \
  } while (0)

#define BAR() __builtin_amdgcn_s_barrier()

    // ---- prologue: tile0 full (8 loads) + A0,B0(tile1) (4 loads)
    STG_AH(0, 0, 0); STG_AH(0, 1, 0); STG_BH(0, 0, 0); STG_BH(0, 1, 0);
    STG_AH(1, 0, 1); STG_BH(1, 0, 1);
    asm volatile("s_waitcnt vmcnt(4)" ::: "memory");  // tile0 resident
    BAR();
    LD_AL(0, 0); LD_BK(0, b0k, 0);                    // g0(0)

    // MODE: 2 steady; 1 = j=62 (p0 stage normal, p3: no stage, vmcnt(0));
    //       0 = j=63 (tail: no stage/sync/g0)
    auto body = [&](int j, auto bfc, auto modec) {
        constexpr int BF   = decltype(bfc)::value;
        constexpr int MODE = decltype(modec)::value;
        constexpr int OF   = BF ^ 1;
        // ---- p0: g1; stage A1,B1(j+1)->OF; c0
        LD_AH(BF, 0);
        if constexpr (MODE >= 1) { STG_AH(OF, 1, j + 1); STG_BH(OF, 1, j + 1); }
        MFMA_C(aL, b0k, 0);                       // c0 (g0, 1 phase old)
        BAR();
        // ---- p1: g2; c1
        LD_AL(BF, 1); LD_BK(BF, b1k, 1);
        MFMA_C(aH, b0k, 4);                       // c1 (g1)
        BAR();
        // ---- p2: g3; c2
        LD_AH(BF, 1);
        MFMA_C(aL, b1k, 0);                       // c2 (g2)
        BAR();
        // ---- p3: stage A0,B0(j+2)->BF; vmcnt; bar; g0(j+1); c3
        if constexpr (MODE == 2) {
            STG_AH(BF, 0, j + 2); STG_BH(BF, 0, j + 2);
            asm volatile("s_waitcnt vmcnt(4)" ::: "memory"); // tile j+1 landed
        } else if constexpr (MODE == 1) {
            asm volatile("s_waitcnt vmcnt(0)" ::: "memory"); // tile 63 landed
        }
        if constexpr (MODE >= 1) {
            BAR();
            LD_AL(OF, 0); LD_BK(OF, b0k, 0);      // g0(j+1) from other buf
        }
        MFMA_C(aH, b1k, 4);                       // c3 (g3)
        BAR();
    };

    for (int j = 0; j < 62; j += 2) {
        body(j,     IC<0>{}, IC<2>{});
        body(j + 1, IC<1>{}, IC<2>{});
    }
    body(62, IC<0>{}, IC<1>{});
    body(63, IC<1>{}, IC<0>{});

    // ---- epilogue: C/D layout col = lane&15, row = (lane>>4)*4 + i
    int q = lane >> 4;
#pragma unroll
    for (int n = 0; n < 4; ++n) {
        int col = n0 + wn * 64 + n * 16 + rl;
        float bv = bias[col];
#pragma unroll
        for (int m = 0; m < 8; ++m) {
#pragma unroll
            for (int i = 0; i < 4; ++i) {
                int row = m0 + wm * 128 + m * 16 + q * 4 + i;
                out[(size_t)row * OUT_DIM + col] = acc[m][n][i] + bv;
            }
        }
    }
#undef STG_AH
#undef STG_BH
#undef RD_A
#undef RD_B
#undef LD_AL
#undef LD_AH
#undef LD_BK
#undef MFMA_C
#undef BAR
}

// ---------------------------------------------------------------- launch
extern "C" void kernel_launch(void* const* d_in, const int* in_sizes, int n_in,
                              void* d_out, int out_size, void* d_ws, size_t ws_size,
                              hipStream_t stream) {
    const float* x     = (const float*)d_in[0];
    const int*   pw    = (const int*)d_in[1];
    const float* norms = (const float*)d_in[2];
    const float* s1    = (const float*)d_in[3];
    const float* s2    = (const float*)d_in[4];
    const float* cent  = (const float*)d_in[5];
    const float* bias  = (const float*)d_in[6];
    float* out = (float*)d_out;

    size_t needX = (size_t)MROWS * IN_DIM * 2;    // 128 MB
    size_t needW = (size_t)OUT_DIM * IN_DIM * 2;  //  32 MB
    if (ws_size < needX + needW) return;

    unsigned short* Xb = (unsigned short*)d_ws;
    unsigned short* Wb = (unsigned short*)((char*)d_ws + needX);

    convert_x<<<2048, 256, 0, stream>>>(x, Xb, MROWS * IN_DIM / 8);
    decode_w<<<(OUT_DIM * 32) / 4, 256, 0, stream>>>(pw, norms, s1, s2, cent, Wb);
    gemm_bf16<<<(MROWS / 256) * (OUT_DIM / 256), 512, 0, stream>>>(Xb, Wb, bias, out);
}

// Round 14
// 644.698 us; speedup vs baseline: 1.2194x; 1.2194x over previous
//
#include <hip/hip_runtime.h>
#include <hip/hip_bf16.h>

typedef __attribute__((ext_vector_type(8))) short short8;
typedef __attribute__((ext_vector_type(4))) float floatx4;

#define IN_DIM  4096
#define OUT_DIM 4096
#define MROWS   16384
#define GSIZE   128

template <int N> struct IC { static constexpr int value = N; };

__device__ __forceinline__ unsigned short f2bf(float f) {
    unsigned int u = __builtin_bit_cast(unsigned int, f);
    u = (u + 0x7fffu + ((u >> 16) & 1u)) >> 16;
    return (unsigned short)u;
}

#define GLD16(gsrc, ldst)                                                     \
    __builtin_amdgcn_global_load_lds(                                         \
        (const __attribute__((address_space(1))) unsigned int*)(const void*)(gsrc), \
        (__attribute__((address_space(3))) unsigned int*)(void*)(ldst),       \
        16, 0, 0)

// ---------------------------------------------------------------- convert x
__global__ void convert_x(const float* __restrict__ x,
                          unsigned short* __restrict__ xb, int n8) {
    int stride = gridDim.x * blockDim.x;
    for (int i = blockIdx.x * blockDim.x + threadIdx.x; i < n8; i += stride) {
        const float4* xf = (const float4*)x;
        float4 f0 = xf[2 * i];
        float4 f1 = xf[2 * i + 1];
        union { unsigned short u[8]; uint4 v; } pk;
        pk.u[0] = f2bf(f0.x); pk.u[1] = f2bf(f0.y);
        pk.u[2] = f2bf(f0.z); pk.u[3] = f2bf(f0.w);
        pk.u[4] = f2bf(f1.x); pk.u[5] = f2bf(f1.y);
        pk.u[6] = f2bf(f1.z); pk.u[7] = f2bf(f1.w);
        ((uint4*)xb)[i] = pk.v;
    }
}

// ---------------------------------------------------------------- decode W
__global__ void decode_w(const int* __restrict__ pw,
                         const float* __restrict__ norms,
                         const float* __restrict__ s1,
                         const float* __restrict__ s2,
                         const float* __restrict__ cent,
                         unsigned short* __restrict__ W) {
    int row  = blockIdx.x * 4 + (threadIdx.x >> 6);
    int lane = threadIdx.x & 63;
    float nrm = norms[row];
    int c0 = pw[(size_t)row * GSIZE + lane];
    int c1 = pw[(size_t)row * GSIZE + lane + 64];
    float e0 = cent[c0] * nrm * s2[lane];
    float e1 = cent[c1] * nrm * s2[lane + 64];
#pragma unroll
    for (int it = 0; it < 7; ++it) {
        float a = e0, b = e1;
        e0 = a + b;
        e1 = a - b;
    }
    const float inv = 0.08838834764831845f; // 1/sqrt(128)
    int o = row >> 5, g = row & 31;
    unsigned short* wr = W + (size_t)o * IN_DIM + g * GSIZE;
    wr[lane]      = f2bf(e0 * inv * s1[lane]);
    wr[lane + 64] = f2bf(e1 * inv * s1[lane + 64]);
}

// ---------------------------------------------------------------- GEMM
// R6's 8-phase quadrant schedule with the MID-BARRIER REMOVED: one barrier
// per phase. Phase = [reads || stage -> lgkmcnt(0) -> setprio + 16 MFMA ->
// s_barrier]. The mid-barrier certified nothing (WAR needs only own-lgkm0
// before the end-barrier) but forced all 8 waves to alternate [drain][MFMA]
// in lockstep -- removing it lets wave skew overlap one wave's MFMA with
// another's DS drain.
//
// 256x256 tile, BK=64, 8 waves (2M x 4N), 16x16x32 MFMA, chunk-XOR swizzle
// (0 conflicts). Quadrants: p0 (m0-3,n0-1) reads B n0-1 + A m0-3 (12);
// p1 (m0-3,n2-3) reads B n2-3 (4); p2 (m4-7,n0-1) reads A m4-7 (8);
// p3 (m4-7,n2-3) reads 0.
// Stage plan at tile j (BF=j&1): p0: A1(j+1)->BF^1 [A1 of BF^1 last read
// p2(j-1), certified by BAR(p2,j-1)]; p1: A0(j+2)->BF [read p0]; p2:
// B0(j+2)->BF [read p0]; p3: B1(j+2)->BF [read p1]; then vmcnt(6) leaves
// exactly {A0,B0,B1}(j+2) outstanding -> A1(j+1)+older landed -> tile j+1
// resident; BAR globalizes. Reads at p0(j+1) are pinned after the vmcnt by
// its "memory" clobber.
__global__ __launch_bounds__(512, 2)
void gemm_bf16(const unsigned short* __restrict__ Xg,
               const unsigned short* __restrict__ Wg,
               const float* __restrict__ bias,
               float* __restrict__ out) {
    __shared__ unsigned short As[2][256][64];
    __shared__ unsigned short Bs[2][256][64];

    // bijective XCD swizzle (1024 blocks % 8 == 0); consecutive ids share mt
    int id = (blockIdx.x & 7) * 128 + (blockIdx.x >> 3);
    int mt = id >> 4, nt = id & 15;
    int m0 = mt * 256, n0 = nt * 256;

    int tid  = threadIdx.x;
    int lane = tid & 63;
    int wid  = tid >> 6;
    int wm = wid >> 2, wn = wid & 3;   // wave tile: rows wm*128+, cols wn*64+

    // staging: thread handles 16B phys chunk cp0 of rows sr0 / sr0+64(+128)
    int sr0 = tid >> 3;        // 0..63
    int cp0 = tid & 7;         // physical chunk position
    int sg0 = cp0 ^ (sr0 & 7); // global chunk (inverse swizzle)

// A halves interleaved: h=0 -> rows [0,64)u[128,192) (m-frags 0-3),
//                       h=1 -> rows [64,128)u[192,256) (m-frags 4-7)
#define STG_AH(bufc, h, j) do {                                               \
    const unsigned short* _s =                                                \
        Xg + (size_t)(m0 + (h)*64 + sr0) * IN_DIM + (size_t)(j)*64 + sg0*8;   \
    GLD16(_s,                 &As[bufc][(h)*64 + sr0][cp0 * 8]);              \
    GLD16(_s + 128 * IN_DIM,  &As[bufc][128 + (h)*64 + sr0][cp0 * 8]);        \
  } while (0)
// B halves contiguous: h=0 -> rows [0,128), h=1 -> rows [128,256)
#define STG_BH(bufc, h, j) do {                                               \
    const unsigned short* _s =                                                \
        Wg + (size_t)(n0 + (h)*128 + sr0) * IN_DIM + (size_t)(j)*64 + sg0*8;  \
    GLD16(_s,                &Bs[bufc][(h)*128 + sr0][cp0 * 8]);              \
    GLD16(_s + 64 * IN_DIM,  &Bs[bufc][(h)*128 + sr0 + 64][cp0 * 8]);         \
  } while (0)

    int rl = lane & 15, kc = lane >> 4;
    short8 a_[8][2], b_[4][2];
    floatx4 acc[8][4] = {};

#define LD_A(BFc, m, ks) do {                                                 \
    int row_ = wm * 128 + (m)*16 + rl;                                        \
    a_[m][ks] = *(const short8*)&As[BFc][row_][((((ks)*4 + kc) ^ (rl & 7)) << 3)]; \
  } while (0)
#define LD_B(BFc, n, ks) do {                                                 \
    int row_ = wn * 64 + (n)*16 + rl;                                         \
    b_[n][ks] = *(const short8*)&Bs[BFc][row_][((((ks)*4 + kc) ^ (rl & 7)) << 3)]; \
  } while (0)

#define LGKM0() asm volatile("s_waitcnt lgkmcnt(0)" ::: "memory")
#define BAR()   __builtin_amdgcn_s_barrier()

#define MFMA_Q(mh, nh) do {                                                   \
    __builtin_amdgcn_s_setprio(1);                                            \
    _Pragma("unroll") for (int ks = 0; ks < 2; ++ks) {                        \
      _Pragma("unroll") for (int m = 4*(mh); m < 4*(mh) + 4; ++m) {           \
        _Pragma("unroll") for (int n = 2*(nh); n < 2*(nh) + 2; ++n)           \
          acc[m][n] = __builtin_amdgcn_mfma_f32_16x16x32_bf16(                \
              a_[m][ks], b_[n][ks], acc[m][n], 0, 0, 0);                      \
      }                                                                       \
    }                                                                         \
    __builtin_amdgcn_s_setprio(0);                                            \
  } while (0)

    // ---- prologue: tile0 full (8 loads); A0,B0,B1 of tile1 (6 loads)
    STG_BH(0, 0, 0); STG_BH(0, 1, 0); STG_AH(0, 0, 0); STG_AH(0, 1, 0);
    STG_AH(1, 0, 1); STG_BH(1, 0, 1); STG_BH(1, 1, 1);
    asm volatile("s_waitcnt vmcnt(6)" ::: "memory");  // tile0 resident
    BAR();

    // MODE: 2 = steady; 1 = j=62 (stage A1(63) only, vmcnt(0)); 0 = j=63
    auto body = [&](int j, auto bfc, auto modec) {
        constexpr int BF   = decltype(bfc)::value;
        constexpr int MODE = decltype(modec)::value;
        // ---- p0: quadrant (m0-3, n0-1); 12 reads; stage A1(j+1)
        LD_B(BF, 0, 0); LD_B(BF, 0, 1); LD_B(BF, 1, 0); LD_B(BF, 1, 1);
        LD_A(BF, 0, 0); LD_A(BF, 0, 1); LD_A(BF, 1, 0); LD_A(BF, 1, 1);
        LD_A(BF, 2, 0); LD_A(BF, 2, 1); LD_A(BF, 3, 0); LD_A(BF, 3, 1);
        if constexpr (MODE >= 1) STG_AH(BF ^ 1, 1, j + 1);
        LGKM0();
        MFMA_Q(0, 0);
        BAR();
        // ---- p1: quadrant (m0-3, n2-3); 4 reads; stage A0(j+2)
        LD_B(BF, 2, 0); LD_B(BF, 2, 1); LD_B(BF, 3, 0); LD_B(BF, 3, 1);
        if constexpr (MODE == 2) STG_AH(BF, 0, j + 2);
        LGKM0();
        MFMA_Q(0, 1);
        BAR();
        // ---- p2: quadrant (m4-7, n0-1); 8 reads; stage B0(j+2)
        LD_A(BF, 4, 0); LD_A(BF, 4, 1); LD_A(BF, 5, 0); LD_A(BF, 5, 1);
        LD_A(BF, 6, 0); LD_A(BF, 6, 1); LD_A(BF, 7, 0); LD_A(BF, 7, 1);
        if constexpr (MODE == 2) STG_BH(BF, 0, j + 2);
        LGKM0();
        MFMA_Q(1, 0);
        BAR();
        // ---- p3: quadrant (m4-7, n2-3); 0 reads; stage B1(j+2); vmcnt
        if constexpr (MODE == 2) {
            STG_BH(BF, 1, j + 2);
            asm volatile("s_waitcnt vmcnt(6)" ::: "memory"); // tile j+1 landed
        } else if constexpr (MODE == 1) {
            asm volatile("s_waitcnt vmcnt(0)" ::: "memory");
        }
        MFMA_Q(1, 1);
        BAR();
    };

    for (int j = 0; j < 62; j += 2) {
        body(j,     IC<0>{}, IC<2>{});
        body(j + 1, IC<1>{}, IC<2>{});
    }
    body(62, IC<0>{}, IC<1>{});
    body(63, IC<1>{}, IC<0>{});

    // ---- epilogue: C/D layout col = lane&15, row = (lane>>4)*4 + i
    int q = lane >> 4;
#pragma unroll
    for (int n = 0; n < 4; ++n) {
        int col = n0 + wn * 64 + n * 16 + rl;
        float bv = bias[col];
#pragma unroll
        for (int m = 0; m < 8; ++m) {
#pragma unroll
            for (int i = 0; i < 4; ++i) {
                int row = m0 + wm * 128 + m * 16 + q * 4 + i;
                out[(size_t)row * OUT_DIM + col] = acc[m][n][i] + bv;
            }
        }
    }
#undef STG_AH
#undef STG_BH
#undef LD_A
#undef LD_B
#undef LGKM0
#undef BAR
#undef MFMA_Q
}

// ---------------------------------------------------------------- launch
extern "C" void kernel_launch(void* const* d_in, const int* in_sizes, int n_in,
                              void* d_out, int out_size, void* d_ws, size_t ws_size,
                              hipStream_t stream) {
    const float* x     = (const float*)d_in[0];
    const int*   pw    = (const int*)d_in[1];
    const float* norms = (const float*)d_in[2];
    const float* s1    = (const float*)d_in[3];
    const float* s2    = (const float*)d_in[4];
    const float* cent  = (const float*)d_in[5];
    const float* bias  = (const float*)d_in[6];
    float* out = (float*)d_out;

    size_t needX = (size_t)MROWS * IN_DIM * 2;    // 128 MB
    size_t needW = (size_t)OUT_DIM * IN_DIM * 2;  //  32 MB
    if (ws_size < needX + needW) return;

    unsigned short* Xb = (unsigned short*)d_ws;
    unsigned short* Wb = (unsigned short*)((char*)d_ws + needX);

    convert_x<<<2048, 256, 0, stream>>>(x, Xb, MROWS * IN_DIM / 8);
    decode_w<<<(OUT_DIM * 32) / 4, 256, 0, stream>>>(pw, norms, s1, s2, cent, Wb);
    gemm_bf16<<<(MROWS / 256) * (OUT_DIM / 256), 512, 0, stream>>>(Xb, Wb, bias, out);
}